// Round 1
// baseline (80.785 us; speedup 1.0000x reference)
//
#include <hip/hip_runtime.h>
#include <math.h>

// LogSplineFilterFullVI: out[i] = exp(log_tau2 + s(log(lam[i]+1e-6)) - s0)
// s(t) = cubic B-spline (J=12, 16 clamped knots, 9 uniform interior spans).
// Strategy: per-block f64 prep folds spline+w+log_tau2-s0 into 9 span-local
// cubic monomial coeff sets in LDS; per-element work is log -> span -> Horner -> exp.
// Memory-bound: 33.6 MB traffic -> ~5.3 us floor at 6.3 TB/s.

#define JB 12

constexpr double TMIN = -13.815510557964274;   // math.log(1e-6)
constexpr double TMAX = 0.6931476805598203;    // math.log(2.0 + 1e-6)
constexpr double STEP = (TMAX - TMIN) / 9.0;   // matches np.linspace step

__host__ __device__ constexpr double kn(int i) {
  return (i <= 3) ? TMIN : ((i >= 12) ? TMAX : ((double)(i - 3)) * STEP + TMIN);
}

struct Tables {
  double inv1[3][JB];
  double inv2[3][JB];
};

constexpr Tables make_tables() {
  Tables T{};
  for (int k = 1; k <= 3; k++) {
    for (int i = 0; i < JB; i++) {
      double d1 = kn(i + k) - kn(i);
      double d2 = kn(i + k + 1) - kn(i + 1);
      T.inv1[k - 1][i] = (d1 != 0.0) ? 1.0 / d1 : 0.0;
      T.inv2[k - 1][i] = (d2 != 0.0) ? 1.0 / d2 : 0.0;
    }
  }
  return T;
}

constexpr Tables TBL = make_tables();

// Faithful f64 replication of the reference Cox-de Boor recursion (half-open
// intervals, zero-padded shift). Only called at points strictly inside spans
// (plus t == TMIN, which lands in [kn(3), kn(4)) correctly).
__device__ __forceinline__ double spline_eval_f64(double t, const double* w) {
  double B[JB + 1];
#pragma unroll
  for (int i = 0; i < JB; i++)
    B[i] = (t >= kn(i) && t < kn(i + 1)) ? 1.0 : 0.0;
  B[JB] = 0.0;
#pragma unroll
  for (int k = 1; k <= 3; k++) {
#pragma unroll
    for (int i = 0; i < JB; i++) {
      double a = (t - kn(i)) * TBL.inv1[k - 1][i];
      double b = (kn(i + k + 1) - t) * TBL.inv2[k - 1][i];
      B[i] = a * B[i] + b * B[i + 1];   // ascending i: B[i+1] still "old" level
    }
  }
  double s = 0.0;
#pragma unroll
  for (int i = 0; i < JB; i++) s += B[i] * w[i];
  return s;
}

__device__ __forceinline__ float eval1(float lamv, const float4* coef, float Kf) {
  const float TMIN_F = (float)TMIN;
  const float TMAX_F = (float)TMAX;
  const float H_F    = (float)STEP;
  const float INVH_F = (float)(1.0 / STEP);

  float x = lamv + 1e-6f;
  float t = __logf(x);
  float r = t - TMIN_F;
  int span = (int)(r * INVH_F);
  span = span < 0 ? 0 : (span > 8 ? 8 : span);
  float u = fmaf((float)(-span), H_F, r);
  float4 c = coef[span];
  float p = fmaf(fmaf(fmaf(c.w, u, c.z), u, c.y), u, c.x);  // K folded into c.x
  // Reference: t < knots[0] or t > knots[-1] -> all-zero basis -> s = 0.
  // (t == TMAX handled by span clamp: poly(u=h) == w[11] by continuity.)
  bool in_range = (t >= TMIN_F) && (t <= TMAX_F);
  return __expf(in_range ? p : Kf);
}

__global__ void __launch_bounds__(256) logspline_kernel(
    const float* __restrict__ lam,
    const float* __restrict__ mu_lt,
    const float* __restrict__ lst,
    const float* __restrict__ mu_w,
    const float* __restrict__ Lw,
    const float* __restrict__ eps_tau,
    const float* __restrict__ eps_w,
    float* __restrict__ out) {
  __shared__ double w_sh[JB];
  __shared__ double y_sh[9][4];
  __shared__ double K_sh;
  __shared__ float4 coef_sh[9];
  __shared__ float  Kf_sh;

  const int tid = threadIdx.x;

  // Phase 1: w = mu_w + L_w @ eps_w (f64; reference is f32 -> diff ~1e-7, ok)
  if (tid < JB) {
    double acc = (double)mu_w[tid];
#pragma unroll
    for (int k = 0; k < JB; k++)
      acc += (double)Lw[tid * JB + k] * (double)eps_w[k];
    w_sh[tid] = acc;
  }
  __syncthreads();

  // Phase 2: sample the spline at 4 strictly-interior nodes per span;
  // also compute K = log_tau2 - s0.
  if (tid < 36) {
    int s = tid >> 2, q = tid & 3;
    double u = ((double)(2 * q + 1)) * STEP * 0.125;  // h/8, 3h/8, 5h/8, 7h/8
    double t = kn(3 + s) + u;
    y_sh[s][q] = spline_eval_f64(t, w_sh);
  } else if (tid == 36) {
    double lt = (double)mu_lt[0] + exp((double)lst[0]) * (double)eps_tau[0];
    double s0 = spline_eval_f64(TMIN, w_sh);
    K_sh = lt - s0;
  }
  __syncthreads();

  // Phase 3: Newton divided differences -> monomial coeffs in u = t - kn(3+s).
  // Exact for a cubic; done in f64 so cancellation is harmless.
  if (tid < 9) {
    const double d  = STEP * 0.25;
    const double n0 = STEP * 0.125, n1 = STEP * 0.375, n2 = STEP * 0.625;
    double y0 = y_sh[tid][0], y1 = y_sh[tid][1], y2 = y_sh[tid][2], y3 = y_sh[tid][3];
    double f01 = (y1 - y0) / d, f12 = (y2 - y1) / d, f23 = (y3 - y2) / d;
    double f012 = (f12 - f01) / (2.0 * d), f123 = (f23 - f12) / (2.0 * d);
    double f0123 = (f123 - f012) / (3.0 * d);
    double c3 = f0123;
    double c2 = f012 - f0123 * (n0 + n1 + n2);
    double c1 = f01 - f012 * (n0 + n1) + f0123 * (n0 * n1 + n0 * n2 + n1 * n2);
    double c0 = y0 - f01 * n0 + f012 * (n0 * n1) - f0123 * (n0 * n1 * n2) + K_sh;
    coef_sh[tid] = make_float4((float)c0, (float)c1, (float)c2, (float)c3);
  }
  if (tid == 0) Kf_sh = (float)K_sh;
  __syncthreads();

  const float Kf = Kf_sh;
  const float4* lam4 = (const float4*)lam;
  float4* out4 = (float4*)out;

  // 1024 blocks x 256 threads x 4 float4 = 4,194,304 elements
  const int base = blockIdx.x * 1024 + tid;
#pragma unroll
  for (int it = 0; it < 4; it++) {
    int idx = base + it * 256;
    float4 v = lam4[idx];
    float4 rr;
    rr.x = eval1(v.x, coef_sh, Kf);
    rr.y = eval1(v.y, coef_sh, Kf);
    rr.z = eval1(v.z, coef_sh, Kf);
    rr.w = eval1(v.w, coef_sh, Kf);
    out4[idx] = rr;
  }
}

extern "C" void kernel_launch(void* const* d_in, const int* in_sizes, int n_in,
                              void* d_out, int out_size, void* d_ws, size_t ws_size,
                              hipStream_t stream) {
  const float* lam     = (const float*)d_in[0];
  const float* mu_lt   = (const float*)d_in[1];
  const float* lst     = (const float*)d_in[2];
  const float* mu_w    = (const float*)d_in[3];
  const float* Lw      = (const float*)d_in[4];
  const float* eps_tau = (const float*)d_in[5];
  const float* eps_w   = (const float*)d_in[6];
  float* out = (float*)d_out;

  // N = 4194304 = 1024 blocks * 256 threads * 16 elems
  logspline_kernel<<<1024, 256, 0, stream>>>(lam, mu_lt, lst, mu_w, Lw,
                                             eps_tau, eps_w, out);
}